// Round 2
// baseline (710.648 us; speedup 1.0000x reference)
//
#include <hip/hip_runtime.h>
#include <hip/hip_bf16.h>

// Superpoint MAE: fused MLP (32->64->128, relu) + segment_max(50K), MI355X.
// Input dtype (bf16 vs fp32) is AMBIGUOUS from the host side -> on-device
// probe writes flags into d_ws; per-dtype kernel instantiations early-exit
// on the wrong flag. relu >= 0 => integer atomicMax on fp32 bits == float max,
// and 0-init matches the reference's empty-segment -> 0 guard.
//
//  flags[0] : 1 = X/W are bf16, 0 = fp32       (probed from X bit patterns)
//  flags[1] : 1 = indices int64, 0 = int32     (probed from odd 32-bit words)
//
//  fp32 path : atomicMax fp32 bits directly into d_out (fp32 out assumed)
//  bf16 path : atomicMax into fp32 ws accumulator, then fp32->bf16 pass
//              (fallback if ws too small: CAS on packed bf16 pairs in d_out)

#define NPTS  1500000
#define NSEG  50000
#define NTILES (NPTS / 16)   // 93750, exact

typedef __attribute__((ext_vector_type(8))) short short8;
typedef __attribute__((ext_vector_type(4))) float floatx4;
typedef __attribute__((ext_vector_type(4))) unsigned short ushortx4;

__device__ __forceinline__ unsigned short f2bf(float f) {
    unsigned int x = __float_as_uint(f);
    x += 0x7FFFu + ((x >> 16) & 1u);   // RNE; finite inputs only
    return (unsigned short)(x >> 16);
}
__device__ __forceinline__ float bf2f(unsigned short b) {
    return __uint_as_float(((unsigned int)b) << 16);
}

// ---------------- dtype probe ----------------
__global__ void probe_dtypes(const unsigned int* __restrict__ Xw,
                             const unsigned int* __restrict__ idxw,
                             unsigned int* __restrict__ flags)
{
    __shared__ int cnt[2];
    if (threadIdx.x < 2) cnt[threadIdx.x] = 0;
    __syncthreads();
    // bf16 test: both 16b halves of each word must look like sane bf16 normals
    int c = 0;
    #pragma unroll
    for (int j = 0; j < 4; ++j) {
        unsigned u  = Xw[threadIdx.x * 4 + j];
        unsigned he = (u >> 23) & 0xFFu;   // exponent field of high half
        unsigned le = (u >> 7)  & 0xFFu;   // exponent field of low half
        c += (he >= 100u && he <= 140u && le >= 100u && le <= 140u) ? 1 : 0;
    }
    // int64 test: high words (odd 32b words) of idx all zero if int64
    int nz = 0;
    #pragma unroll
    for (int j = 0; j < 2; ++j)
        nz += (idxw[(threadIdx.x * 2 + j) * 2 + 1] != 0u) ? 1 : 0;
    atomicAdd(&cnt[0], c);
    atomicAdd(&cnt[1], nz);
    __syncthreads();
    if (threadIdx.x == 0) {
        flags[0] = (cnt[0] >= 512) ? 1u : 0u;  // bf16: ~1023/1024, fp32: ~164/1024
        flags[1] = (cnt[1] < 256) ? 1u : 0u;   // int64: 0 nonzero, int32: ~512
    }
}

// ---------------- flag-aware d_out zeroing ----------------
__global__ __launch_bounds__(256)
void zero_out(const unsigned int* __restrict__ flags, unsigned int* __restrict__ out)
{
    const int n = (flags[0] == 1u) ? (NSEG * 128 / 2) : (NSEG * 128); // uints
    const int i = blockIdx.x * 256 + threadIdx.x;
    if (i < n) out[i] = 0u;
}

// ---------------- fused MLP + segment-max ----------------
// DT: 1 = bf16 inputs, 0 = fp32 inputs.  SINK: 1 = fp32 ws accum, 0 = direct d_out.
template<int DT, int SINK>
__global__ __launch_bounds__(256)
void sp_mlp_max(const unsigned int* __restrict__ flags,
                const void* __restrict__ Xv,
                const void* __restrict__ sidxv,
                const void* __restrict__ W1v,
                const void* __restrict__ B1v,
                const void* __restrict__ W2v,
                const void* __restrict__ B2v,
                float* __restrict__ acc,
                unsigned int* __restrict__ outp)
{
    if (flags[0] != (unsigned)DT) return;          // wrong-dtype instantiation
    const int idx64 = (int)flags[1];

    // per-wave h1 staging (16 pts x 64 cols), stride 72: 16B-aligned b128 reads
    __shared__ __align__(16) unsigned short h1s[4][16 * 72];

    const int tid  = threadIdx.x;
    const int wave = tid >> 6;
    const int lane = tid & 63;
    const int quad = lane >> 4;
    const int l16  = lane & 15;

    const unsigned short* W1u = (const unsigned short*)W1v;
    const float*          W1f = (const float*)W1v;
    const unsigned short* W2u = (const unsigned short*)W2v;
    const float*          W2f = (const float*)W2v;
    const unsigned short* B1u = (const unsigned short*)B1v;
    const float*          B1f = (const float*)B1v;
    const unsigned short* B2u = (const unsigned short*)B2v;
    const float*          B2f = (const float*)B2v;
    const int*            sidx = (const int*)sidxv;

    // ---- preload wave-invariant B fragments: B[k = quad*8+j][n = l16+16*t] ----
    short8 w1f[4];
    #pragma unroll
    for (int t = 0; t < 4; ++t)
        #pragma unroll
        for (int j = 0; j < 8; ++j) {
            const int e = (quad * 8 + j) * 64 + t * 16 + l16;
            w1f[t][j] = DT ? (short)W1u[e] : (short)f2bf(W1f[e]);
        }

    short8 w2f[2][8];
    #pragma unroll
    for (int kt = 0; kt < 2; ++kt)
        #pragma unroll
        for (int t = 0; t < 8; ++t)
            #pragma unroll
            for (int j = 0; j < 8; ++j) {
                const int e = (kt * 32 + quad * 8 + j) * 128 + t * 16 + l16;
                w2f[kt][t][j] = DT ? (short)W2u[e] : (short)f2bf(W2f[e]);
            }

    float b1v[4], b2v[8];
    #pragma unroll
    for (int t = 0; t < 4; ++t) b1v[t] = DT ? bf2f(B1u[t * 16 + l16]) : B1f[t * 16 + l16];
    #pragma unroll
    for (int t = 0; t < 8; ++t) b2v[t] = DT ? bf2f(B2u[t * 16 + l16]) : B2f[t * 16 + l16];

    unsigned short* hrow = h1s[wave];
    const int gw = blockIdx.x * 4 + wave;
    const int nw = gridDim.x * 4;

    for (int tile = gw; tile < NTILES; tile += nw) {
        const int pbase = tile * 16;

        // A fragment: point (pbase+l16), feats [quad*8, quad*8+8)
        short8 a;
        if (DT) {
            a = *(const short8*)((const unsigned short*)Xv
                                 + (size_t)(pbase + l16) * 32 + quad * 8);
        } else {
            const float* xf = (const float*)Xv + (size_t)(pbase + l16) * 32 + quad * 8;
            const floatx4 f0 = *(const floatx4*)xf;
            const floatx4 f1 = *(const floatx4*)(xf + 4);
            #pragma unroll
            for (int j = 0; j < 4; ++j) {
                a[j]     = (short)f2bf(f0[j]);
                a[4 + j] = (short)f2bf(f1[j]);
            }
        }

        // ---- layer 1: h1 = relu(A*W1 + b1) ----
        #pragma unroll
        for (int t = 0; t < 4; ++t) {
            floatx4 c4 = {0.f, 0.f, 0.f, 0.f};
            c4 = __builtin_amdgcn_mfma_f32_16x16x32_bf16(a, w1f[t], c4, 0, 0, 0);
            #pragma unroll
            for (int r = 0; r < 4; ++r) {   // D[row=quad*4+r][col=l16]
                float v = fmaxf(c4[r] + b1v[t], 0.f);
                hrow[(quad * 4 + r) * 72 + t * 16 + l16] = f2bf(v);
            }
        }

        // wave-private LDS round-trip: drain lgkmcnt only (atomics stay in flight)
        __builtin_amdgcn_sched_barrier(0);
        __builtin_amdgcn_s_waitcnt(0xC07F);
        __builtin_amdgcn_sched_barrier(0);

        // layer2 A frags: A[m=l16][k=kt*32+quad*8+j]
        const short8 h0 = *(const short8*)(hrow + l16 * 72 +      quad * 8);
        const short8 h1 = *(const short8*)(hrow + l16 * 72 + 32 + quad * 8);

        int segs[4];
        #pragma unroll
        for (int r = 0; r < 4; ++r) {
            const int p = pbase + quad * 4 + r;
            segs[r] = idx64 ? sidx[2 * p] : sidx[p];   // little-endian low word
        }

        // ---- layer 2: 8 col-tiles, K=64 as two K=32 MFMAs ----
        #pragma unroll
        for (int t = 0; t < 8; ++t) {
            floatx4 c4 = {0.f, 0.f, 0.f, 0.f};
            c4 = __builtin_amdgcn_mfma_f32_16x16x32_bf16(h0, w2f[0][t], c4, 0, 0, 0);
            c4 = __builtin_amdgcn_mfma_f32_16x16x32_bf16(h1, w2f[1][t], c4, 0, 0, 0);
            const int c = t * 16 + l16;
            #pragma unroll
            for (int r = 0; r < 4; ++r) {
                const float v = fmaxf(c4[r] + b2v[t], 0.f);
                const unsigned s = (unsigned)segs[r];
                if (DT == 0) {
                    // fp32 out: v>=0 -> int max == float max on bit pattern
                    if (s < NSEG) atomicMax((int*)outp + (s * 128 + c), __float_as_int(v));
                } else if (SINK == 1) {
                    if (s < NSEG) atomicMax((int*)acc + (s * 128 + c), __float_as_int(v));
                } else {
                    // CAS packed bf16 pairs directly in bf16 d_out
                    unsigned short mb = f2bf(v);
                    unsigned int ob =
                        (unsigned int)(unsigned short)__shfl_xor((int)mb, 1, 64);
                    if ((lane & 1) == 0 && s < NSEG) {
                        unsigned int mine = (ob << 16) | (unsigned int)mb;
                        unsigned int* p = outp + ((s * 128 + c) >> 1);
                        unsigned int old = *(volatile unsigned int*)p;
                        while (1) {
                            unsigned int lo = (old & 0xFFFFu) > (mine & 0xFFFFu)
                                              ? (old & 0xFFFFu) : (mine & 0xFFFFu);
                            unsigned int hi = (old >> 16) > (mine >> 16)
                                              ? (old >> 16) : (mine >> 16);
                            unsigned int nv = (hi << 16) | lo;
                            if (nv == old) break;
                            unsigned int pr = atomicCAS(p, old, nv);
                            if (pr == old) break;
                            old = pr;
                        }
                    }
                }
            }
        }
    }
}

// ---------------- fp32 ws -> bf16 d_out (bf16 path only) ----------------
__global__ __launch_bounds__(256)
void ws_to_bf16(const unsigned int* __restrict__ flags,
                const float* __restrict__ acc, unsigned short* __restrict__ out)
{
    if (flags[0] != 1u) return;
    const int i = blockIdx.x * 256 + threadIdx.x;
    if (i < NSEG * 128 / 4) {
        floatx4 v = ((const floatx4*)acc)[i];
        ushortx4 o;
        #pragma unroll
        for (int j = 0; j < 4; ++j) o[j] = f2bf(v[j]);
        ((ushortx4*)out)[i] = o;
    }
}

extern "C" void kernel_launch(void* const* d_in, const int* in_sizes, int n_in,
                              void* d_out, int out_size, void* d_ws, size_t ws_size,
                              hipStream_t stream)
{
    const void* X  = d_in[0];
    const void* idx= d_in[1];
    const void* W1 = d_in[2];
    const void* B1 = d_in[3];
    const void* W2 = d_in[4];
    const void* B2 = d_in[5];

    unsigned int* flags = (unsigned int*)d_ws;
    const size_t acc_off   = 64;
    const size_t acc_bytes = (size_t)NSEG * 128 * sizeof(float);
    const bool   has_ws    = ws_size >= acc_off + acc_bytes;
    float* acc = (float*)((char*)d_ws + acc_off);

    probe_dtypes<<<1, 256, 0, stream>>>((const unsigned int*)X,
                                        (const unsigned int*)idx, flags);
    zero_out<<<(NSEG * 128 + 255) / 256, 256, 0, stream>>>(flags, (unsigned int*)d_out);
    if (has_ws) hipMemsetAsync(acc, 0, acc_bytes, stream);

    // fp32 instantiation (always direct into d_out)
    sp_mlp_max<0, 0><<<2048, 256, 0, stream>>>(flags, X, idx, W1, B1, W2, B2,
                                               nullptr, (unsigned int*)d_out);
    if (has_ws) {
        sp_mlp_max<1, 1><<<2048, 256, 0, stream>>>(flags, X, idx, W1, B1, W2, B2,
                                                   acc, (unsigned int*)d_out);
        ws_to_bf16<<<(NSEG * 128 / 4 + 255) / 256, 256, 0, stream>>>(
            flags, acc, (unsigned short*)d_out);
    } else {
        sp_mlp_max<1, 0><<<2048, 256, 0, stream>>>(flags, X, idx, W1, B1, W2, B2,
                                                   nullptr, (unsigned int*)d_out);
    }
}

// Round 3
// 576.831 us; speedup vs baseline: 1.2320x; 1.2320x over previous
//
#include <hip/hip_runtime.h>
#include <hip/hip_bf16.h>

// Superpoint MAE: fused MLP (32->64->128, relu) + segment_max(50K), MI355X.
//
// Round-2 post-mortem: 488us main kernel was ATOMIC-bound (WRITE_SIZE 750MB =
// 192M atomicMax write-through; MfmaUtil 2.5%, HBM 22%). Round 3 removes all
// output atomics: counting-sort points by segment (hist -> scan -> scatter),
// then one wave per segment runs the MFMA MLP over its own points with the
// max kept in registers (tail tiles duplicate the last point - max-neutral),
// one coalesced 256B store per segment.
//
// Probed-at-runtime dtypes (round-1 lesson: idx is int64 on this harness):
//  flags[0]: 1 = X/W bf16 (confirmed by FETCH=97MB), 0 = fp32
//  flags[1]: 1 = indices int64, 0 = int32

#define NPTS  1500000
#define NSEG  50000
#define NSB   196            // scan blocks: 196*256 = 50176 >= NSEG

typedef __attribute__((ext_vector_type(8))) short short8;
typedef __attribute__((ext_vector_type(4))) float floatx4;
typedef __attribute__((ext_vector_type(2))) float floatx2;

__device__ __forceinline__ unsigned short f2bf(float f) {
    unsigned int x = __float_as_uint(f);
    x += 0x7FFFu + ((x >> 16) & 1u);   // RNE; finite inputs only
    return (unsigned short)(x >> 16);
}
__device__ __forceinline__ float bf2f(unsigned short b) {
    return __uint_as_float(((unsigned int)b) << 16);
}

// ---------------- dtype probe ----------------
__global__ void probe_dtypes(const unsigned int* __restrict__ Xw,
                             const unsigned int* __restrict__ idxw,
                             unsigned int* __restrict__ flags)
{
    __shared__ int cnt[2];
    if (threadIdx.x < 2) cnt[threadIdx.x] = 0;
    __syncthreads();
    int c = 0;
    #pragma unroll
    for (int j = 0; j < 4; ++j) {
        unsigned u  = Xw[threadIdx.x * 4 + j];
        unsigned he = (u >> 23) & 0xFFu;
        unsigned le = (u >> 7)  & 0xFFu;
        c += (he >= 100u && he <= 140u && le >= 100u && le <= 140u) ? 1 : 0;
    }
    int nz = 0;
    #pragma unroll
    for (int j = 0; j < 2; ++j)
        nz += (idxw[(threadIdx.x * 2 + j) * 2 + 1] != 0u) ? 1 : 0;
    atomicAdd(&cnt[0], c);
    atomicAdd(&cnt[1], nz);
    __syncthreads();
    if (threadIdx.x == 0) {
        flags[0] = (cnt[0] >= 512) ? 1u : 0u;
        flags[1] = (cnt[1] < 256) ? 1u : 0u;
    }
}

__device__ __forceinline__ unsigned read_seg(const unsigned* idxw, int i, int idx64) {
    return idx64 ? idxw[2 * i] : idxw[i];
}

// ---------------- counting sort: histogram ----------------
__global__ __launch_bounds__(256)
void hist_kernel(const unsigned int* __restrict__ flags,
                 const unsigned int* __restrict__ idxw,
                 unsigned int* __restrict__ hist)
{
    const int idx64 = (int)flags[1];
    for (int i = blockIdx.x * 256 + threadIdx.x; i < NPTS; i += gridDim.x * 256) {
        unsigned s = read_seg(idxw, i, idx64);
        if (s < NSEG) atomicAdd(&hist[s], 1u);
    }
}

// ---------------- scan (3 small kernels) ----------------
__device__ __forceinline__ unsigned block_scan_excl(unsigned v, unsigned* s)
{
    const int t = threadIdx.x;
    s[t] = v; __syncthreads();
    #pragma unroll
    for (int off = 1; off < 256; off <<= 1) {
        unsigned x = (t >= off) ? s[t - off] : 0u;
        __syncthreads();
        s[t] += x;
        __syncthreads();
    }
    return s[t] - v;   // exclusive
}

__global__ __launch_bounds__(256)
void scan_partials(const unsigned int* __restrict__ hist, unsigned int* __restrict__ bsums)
{
    __shared__ unsigned s[256];
    const int i = blockIdx.x * 256 + threadIdx.x;
    unsigned v = (i < NSEG) ? hist[i] : 0u;
    block_scan_excl(v, s);
    if (threadIdx.x == 255) bsums[blockIdx.x] = s[255];   // inclusive total
}

__global__ __launch_bounds__(256)
void scan_bsums(unsigned int* __restrict__ bsums)
{
    __shared__ unsigned s[256];
    const int t = threadIdx.x;
    unsigned v = (t < NSB) ? bsums[t] : 0u;
    unsigned e = block_scan_excl(v, s);
    if (t < NSB) bsums[t] = e;
}

__global__ __launch_bounds__(256)
void scan_final(const unsigned int* __restrict__ hist,
                const unsigned int* __restrict__ bsums,
                unsigned int* __restrict__ offs,
                unsigned int* __restrict__ cursor)
{
    __shared__ unsigned s[256];
    const int i = blockIdx.x * 256 + threadIdx.x;
    unsigned v = (i < NSEG) ? hist[i] : 0u;
    unsigned e = block_scan_excl(v, s) + bsums[blockIdx.x];
    if (i < NSEG) { offs[i] = e; cursor[i] = e; }
    if (i == NSEG - 1) offs[NSEG] = e + v;
}

// ---------------- counting sort: scatter point ids ----------------
__global__ __launch_bounds__(256)
void scatter_kernel(const unsigned int* __restrict__ flags,
                    const unsigned int* __restrict__ idxw,
                    unsigned int* __restrict__ cursor,
                    int* __restrict__ sorted)
{
    const int idx64 = (int)flags[1];
    for (int i = blockIdx.x * 256 + threadIdx.x; i < NPTS; i += gridDim.x * 256) {
        unsigned s = read_seg(idxw, i, idx64);
        if (s < NSEG) {
            unsigned pos = atomicAdd(&cursor[s], 1u);
            sorted[pos] = i;
        }
    }
}

// ---------------- segment-centric fused MLP + register max ----------------
// DT: 1 = bf16 inputs/out, 0 = fp32 inputs/out. One wave per segment.
template<int DT>
__global__ __launch_bounds__(256)
void seg_mlp_max(const unsigned int* __restrict__ flags,
                 const void* __restrict__ Xv,
                 const void* __restrict__ W1v,
                 const void* __restrict__ B1v,
                 const void* __restrict__ W2v,
                 const void* __restrict__ B2v,
                 const unsigned int* __restrict__ offs,
                 const int* __restrict__ sorted,
                 void* __restrict__ outv)
{
    if (flags[0] != (unsigned)DT) return;

    // per-wave h1 staging (16 pts x 64 cols), stride 72: 16B-aligned b128 reads
    __shared__ __align__(16) unsigned short h1s[4][16 * 72];

    const int tid  = threadIdx.x;
    const int wave = tid >> 6;
    const int lane = tid & 63;
    const int quad = lane >> 4;
    const int l16  = lane & 15;

    const unsigned short* W1u = (const unsigned short*)W1v;
    const float*          W1f = (const float*)W1v;
    const unsigned short* W2u = (const unsigned short*)W2v;
    const float*          W2f = (const float*)W2v;
    const unsigned short* B1u = (const unsigned short*)B1v;
    const float*          B1f = (const float*)B1v;
    const unsigned short* B2u = (const unsigned short*)B2v;
    const float*          B2f = (const float*)B2v;

    // wave-invariant B fragments: B[k = quad*8+j][n = l16+16*t]
    short8 w1f[4];
    #pragma unroll
    for (int t = 0; t < 4; ++t)
        #pragma unroll
        for (int j = 0; j < 8; ++j) {
            const int e = (quad * 8 + j) * 64 + t * 16 + l16;
            w1f[t][j] = DT ? (short)W1u[e] : (short)f2bf(W1f[e]);
        }
    short8 w2f[2][8];
    #pragma unroll
    for (int kt = 0; kt < 2; ++kt)
        #pragma unroll
        for (int t = 0; t < 8; ++t)
            #pragma unroll
            for (int j = 0; j < 8; ++j) {
                const int e = (kt * 32 + quad * 8 + j) * 128 + t * 16 + l16;
                w2f[kt][t][j] = DT ? (short)W2u[e] : (short)f2bf(W2f[e]);
            }
    float b1v[4], b2v[8];
    #pragma unroll
    for (int t = 0; t < 4; ++t) b1v[t] = DT ? bf2f(B1u[t * 16 + l16]) : B1f[t * 16 + l16];
    #pragma unroll
    for (int t = 0; t < 8; ++t) b2v[t] = DT ? bf2f(B2u[t * 16 + l16]) : B2f[t * 16 + l16];

    unsigned short* hrow = h1s[wave];
    const int gw = blockIdx.x * 4 + wave;
    const int nw = gridDim.x * 4;

    for (int seg = gw; seg < NSEG; seg += nw) {
        const unsigned o0 = offs[seg], o1 = offs[seg + 1];
        const int cnt = (int)(o1 - o0);
        const int nt  = (cnt + 15) >> 4;

        float vmax[8];
        #pragma unroll
        for (int t = 0; t < 8; ++t) vmax[t] = 0.f;

        for (int ti = 0; ti < nt; ++ti) {
            // duplicate the last point for tail lanes: max-neutral
            const int ii  = (int)o0 + ti * 16 + l16;
            const int ci  = min(ii, (int)o1 - 1);
            const int pid = sorted[ci];

            short8 a;
            if (DT) {
                a = *(const short8*)((const unsigned short*)Xv + (size_t)pid * 32 + quad * 8);
            } else {
                const float* xf = (const float*)Xv + (size_t)pid * 32 + quad * 8;
                const floatx4 f0 = *(const floatx4*)xf;
                const floatx4 f1 = *(const floatx4*)(xf + 4);
                #pragma unroll
                for (int j = 0; j < 4; ++j) { a[j] = (short)f2bf(f0[j]); a[4+j] = (short)f2bf(f1[j]); }
            }

            // layer 1: h1 = relu(A*W1 + b1)
            #pragma unroll
            for (int t = 0; t < 4; ++t) {
                floatx4 c4 = {0.f, 0.f, 0.f, 0.f};
                c4 = __builtin_amdgcn_mfma_f32_16x16x32_bf16(a, w1f[t], c4, 0, 0, 0);
                #pragma unroll
                for (int r = 0; r < 4; ++r) {
                    float v = fmaxf(c4[r] + b1v[t], 0.f);
                    hrow[(quad * 4 + r) * 72 + t * 16 + l16] = f2bf(v);
                }
            }

            // wave-private LDS round-trip: drain lgkmcnt only
            __builtin_amdgcn_sched_barrier(0);
            __builtin_amdgcn_s_waitcnt(0xC07F);
            __builtin_amdgcn_sched_barrier(0);

            const short8 h0 = *(const short8*)(hrow + l16 * 72 +      quad * 8);
            const short8 h1 = *(const short8*)(hrow + l16 * 72 + 32 + quad * 8);

            // layer 2 + in-register max (all 16 rows belong to this segment)
            #pragma unroll
            for (int t = 0; t < 8; ++t) {
                floatx4 c4 = {0.f, 0.f, 0.f, 0.f};
                c4 = __builtin_amdgcn_mfma_f32_16x16x32_bf16(h0, w2f[0][t], c4, 0, 0, 0);
                c4 = __builtin_amdgcn_mfma_f32_16x16x32_bf16(h1, w2f[1][t], c4, 0, 0, 0);
                #pragma unroll
                for (int r = 0; r < 4; ++r)
                    vmax[t] = fmaxf(vmax[t], fmaxf(c4[r] + b2v[t], 0.f));
            }
            // reads h0/h1 must complete before next iteration's hrow writes
            __builtin_amdgcn_sched_barrier(0);
            __builtin_amdgcn_s_waitcnt(0xC07F);
            __builtin_amdgcn_sched_barrier(0);
        }

        // cross-quad reduce: all lanes end with col-max for col t*16+l16
        #pragma unroll
        for (int t = 0; t < 8; ++t) {
            vmax[t] = fmaxf(vmax[t], __shfl_xor(vmax[t], 16, 64));
            vmax[t] = fmaxf(vmax[t], __shfl_xor(vmax[t], 32, 64));
        }

        // stage through wave-private LDS for a coalesced 256B row store
        float* fs = (float*)hrow;
        if (quad == 0) {
            #pragma unroll
            for (int t = 0; t < 8; ++t) fs[t * 16 + l16] = vmax[t];
        }
        __builtin_amdgcn_sched_barrier(0);
        __builtin_amdgcn_s_waitcnt(0xC07F);
        __builtin_amdgcn_sched_barrier(0);

        if (DT) {
            unsigned v0 = f2bf(fs[2 * lane]);
            unsigned v1 = f2bf(fs[2 * lane + 1]);
            ((unsigned*)outv)[seg * 64 + lane] = (v1 << 16) | v0;
        } else {
            floatx2 o; o[0] = fs[2 * lane]; o[1] = fs[2 * lane + 1];
            ((floatx2*)outv)[seg * 64 + lane] = o;
        }
        __builtin_amdgcn_sched_barrier(0);
        __builtin_amdgcn_s_waitcnt(0xC07F);   // fs reads done before next seg's writes
        __builtin_amdgcn_sched_barrier(0);
    }
}

extern "C" void kernel_launch(void* const* d_in, const int* in_sizes, int n_in,
                              void* d_out, int out_size, void* d_ws, size_t ws_size,
                              hipStream_t stream)
{
    const void* X   = d_in[0];
    const void* idx = d_in[1];
    const void* W1  = d_in[2];
    const void* B1  = d_in[3];
    const void* W2  = d_in[4];
    const void* B2  = d_in[5];

    // ws layout (bytes): flags 64 | hist 200000 | cursor 200000 | bsums 1024 |
    //                    offs 200004 | sorted 6000000   (~6.4 MB; ws >= 25.6 MB per R2)
    char* w = (char*)d_ws;
    unsigned int* flags  = (unsigned int*)w;               w += 64;
    unsigned int* hist   = (unsigned int*)w;               w += (size_t)NSEG * 4;
    unsigned int* cursor = (unsigned int*)w;               w += (size_t)NSEG * 4;
    unsigned int* bsums  = (unsigned int*)w;               w += 1024;
    unsigned int* offs   = (unsigned int*)w;               w += (size_t)(NSEG + 1) * 4;
    int*          sorted = (int*)w;

    probe_dtypes<<<1, 256, 0, stream>>>((const unsigned int*)X,
                                        (const unsigned int*)idx, flags);
    hipMemsetAsync(hist, 0, (size_t)NSEG * 4, stream);
    hist_kernel<<<2048, 256, 0, stream>>>(flags, (const unsigned int*)idx, hist);
    scan_partials<<<NSB, 256, 0, stream>>>(hist, bsums);
    scan_bsums<<<1, 256, 0, stream>>>(bsums);
    scan_final<<<NSB, 256, 0, stream>>>(hist, bsums, offs, cursor);
    scatter_kernel<<<2048, 256, 0, stream>>>(flags, (const unsigned int*)idx,
                                             cursor, sorted);
    seg_mlp_max<1><<<1024, 256, 0, stream>>>(flags, X, W1, B1, W2, B2,
                                             offs, sorted, d_out);
    seg_mlp_max<0><<<1024, 256, 0, stream>>>(flags, X, W1, B1, W2, B2,
                                             offs, sorted, d_out);
}